// Round 3
// baseline (855.603 us; speedup 1.0000x reference)
//
#include <hip/hip_runtime.h>
#include <hip/hip_bf16.h>
#include <stdint.h>

using bf16 = __hip_bfloat16;

constexpr int N = 3072;
constexpr int D0 = 256;
constexpr int F1 = 128;
constexpr int F2 = 64;
constexpr int HEADS = 4;
constexpr int NW = N / 32;   // 96 mask words per row

#define DI __device__ __forceinline__

DI void storef(float* p, float v) { *p = v; }
DI void storef(bf16* p, float v) { *p = __float2bfloat16(v); }

// ---------------------------------------------------------------- pack adj
__global__ __launch_bounds__(256) void k_pack_adj(const int* __restrict__ adj,
                                                  uint32_t* __restrict__ bits) {
  int idx = blockIdx.x * 256 + threadIdx.x;           // over N*N, j fastest
  unsigned long long m = __ballot(adj[idx] > 0);
  if ((threadIdx.x & 63) == 0) {
    bits[idx >> 5]       = (uint32_t)m;
    bits[(idx >> 5) + 1] = (uint32_t)(m >> 32);
  }
}

// ------------------------------------------------- per-head projection GEMM
// Wh[h][n][o] = sum_k A[n][k] * W[h][k][o]   (all float32)
template <int FIN, int FOUT>
__global__ __launch_bounds__(256) void k_whead(const float* __restrict__ A,
                                               const float* __restrict__ W,
                                               float* __restrict__ Wh) {
  int h  = blockIdx.z;
  int n0 = blockIdx.y * 64;
  int o0 = blockIdx.x * 64;
  int tx = threadIdx.x & 15, ty = threadIdx.x >> 4;
  __shared__ float sA[64][17];
  __shared__ float sB[16][65];
  const float* Wp = W + (size_t)h * FIN * FOUT;
  float acc[4][4] = {};
  for (int k0 = 0; k0 < FIN; k0 += 16) {
#pragma unroll
    for (int q = 0; q < 4; q++)
      sA[ty + 16 * q][tx] = A[(size_t)(n0 + ty + 16 * q) * FIN + k0 + tx];
#pragma unroll
    for (int p = 0; p < 4; p++)
      sB[ty][tx + 16 * p] = Wp[(size_t)(k0 + ty) * FOUT + o0 + tx + 16 * p];
    __syncthreads();
#pragma unroll
    for (int k = 0; k < 16; k++) {
      float a[4], b[4];
#pragma unroll
      for (int q = 0; q < 4; q++) a[q] = sA[ty + 16 * q][k];
#pragma unroll
      for (int p = 0; p < 4; p++) b[p] = sB[k][tx + 16 * p];
#pragma unroll
      for (int q = 0; q < 4; q++)
#pragma unroll
        for (int p = 0; p < 4; p++) acc[q][p] += a[q] * b[p];
    }
    __syncthreads();
  }
#pragma unroll
  for (int q = 0; q < 4; q++)
#pragma unroll
    for (int p = 0; p < 4; p++)
      Wh[((size_t)h * N + n0 + ty + 16 * q) * FOUT + o0 + tx + 16 * p] = acc[q][p];
}

// ---------------------------------------------------------- src/dst vectors
template <int F>
__global__ __launch_bounds__(256) void k_srcdst(const float* __restrict__ Wh,
                                                const float* __restrict__ as_,
                                                const float* __restrict__ ad_,
                                                float* __restrict__ src,
                                                float* __restrict__ dst) {
  int hn   = blockIdx.x * 4 + (threadIdx.x >> 6);
  int lane = threadIdx.x & 63;
  int h    = hn / N;
  const float* rowp = Wh + (size_t)hn * F;
  float s = 0.f, d = 0.f;
  for (int o = lane; o < F; o += 64) {
    float w = rowp[o];
    s += w * as_[h * F + o];
    d += w * ad_[h * F + o];
  }
#pragma unroll
  for (int off = 32; off; off >>= 1) {
    s += __shfl_down(s, off);
    d += __shfl_down(d, off);
  }
  if (lane == 0) { src[hn] = s; dst[hn] = d; }
}

// ------------------------------------------------------- masked flash attn
// out[i][o] = elu( sum_j softmax_j(mask(leakyrelu(src_i+dst_j))) * Wh[j][o] )
// written head-major into hp[n][h*F + o]
template <int F>
__global__ __launch_bounds__(256) void k_attn(const float* __restrict__ Wh,
                                              const float* __restrict__ src,
                                              const float* __restrict__ dst,
                                              const uint32_t* __restrict__ bits,
                                              float* __restrict__ hp) {
  constexpr int FPT = F / 16;           // 8 (F=128) or 4 (F=64)
  int h   = blockIdx.y;
  int i0  = blockIdx.x * 64;
  int tid = threadIdx.x;
  // phase-A role: 4 lanes per row
  int r = tid >> 2, c = tid & 3;
  int row = i0 + r;
  // phase-B role: 16 feature-groups x 16 row-groups (4 rows each)
  int f = tid & 15, g = tid >> 4;

  const float* Whh = Wh + (size_t)h * N * F;
  float srcr = src[h * N + row];
  const uint32_t* brow = bits + (size_t)row * NW;

  __shared__ float sWh[64 * F];
  __shared__ float p_s[64 * 65];
  __shared__ float sDst[64];
  __shared__ float sScale[64];

  float acc[4][FPT];
#pragma unroll
  for (int a = 0; a < 4; a++)
#pragma unroll
    for (int k = 0; k < FPT; k++) acc[a][k] = 0.f;
  float m = -1e30f, s = 0.f;

  for (int j0 = 0; j0 < N; j0 += 64) {
    __syncthreads();   // previous tile fully consumed
    for (int e = tid; e < 64 * F; e += 256) sWh[e] = Whh[(size_t)j0 * F + e];
    if (tid < 64) sDst[tid] = dst[h * N + j0 + tid];
    __syncthreads();

    // ---- phase A: logits + online softmax for this row, 16 j's per lane
    uint32_t word = brow[(j0 >> 5) + (c >> 1)];
    int sh = (c & 1) << 4;
    float v[16];
    float lm = -1e30f;
#pragma unroll
    for (int jj = 0; jj < 16; jj++) {
      float t = srcr + sDst[c * 16 + jj];
      t = t > 0.f ? t : 0.2f * t;
      v[jj] = t;
      if ((word >> (sh + jj)) & 1u) lm = fmaxf(lm, t);
    }
    lm = fmaxf(lm, __shfl_xor(lm, 1));
    lm = fmaxf(lm, __shfl_xor(lm, 2));
    float mnew  = fmaxf(m, lm);
    float scale = __expf(m - mnew);
    float psum  = 0.f;
#pragma unroll
    for (int jj = 0; jj < 16; jj++) {
      float p = ((word >> (sh + jj)) & 1u) ? __expf(v[jj] - mnew) : 0.f;
      p_s[r * 65 + c * 16 + jj] = p;
      psum += p;
    }
    psum += __shfl_xor(psum, 1);
    psum += __shfl_xor(psum, 2);
    s = s * scale + psum;
    m = mnew;
    if (c == 0) sScale[r] = scale;
    __syncthreads();

    // ---- phase B: acc = acc*scale + P @ WhTile  (4 rows x FPT feats/thread)
#pragma unroll
    for (int rr = 0; rr < 4; rr++) {
      float sc = sScale[g * 4 + rr];
#pragma unroll
      for (int k = 0; k < FPT; k++) acc[rr][k] *= sc;
    }
    for (int jj = 0; jj < 64; jj++) {
      float w[FPT];
#pragma unroll
      for (int k = 0; k < FPT; k++) w[k] = sWh[jj * F + f * FPT + k];
#pragma unroll
      for (int rr = 0; rr < 4; rr++) {
        float pv = p_s[(g * 4 + rr) * 65 + jj];
#pragma unroll
        for (int k = 0; k < FPT; k++) acc[rr][k] += pv * w[k];
      }
    }
  }

  __syncthreads();                 // all phase-B reads of sScale done
  if (c == 0) sScale[r] = s;       // publish denominators
  __syncthreads();
#pragma unroll
  for (int rr = 0; rr < 4; rr++) {
    float inv = 1.f / sScale[g * 4 + rr];
    float* op = hp + (size_t)(i0 + g * 4 + rr) * (HEADS * F) + h * F + f * FPT;
#pragma unroll
    for (int k = 0; k < FPT; k++) {
      float val = acc[rr][k] * inv;
      val = val > 0.f ? val : __expf(val) - 1.f;   // elu
      op[k] = val;
    }
  }
}

// ------------------------------------- hp@lin (elu) + hin@res, relu -> out
template <typename TO, int KC, int KR, int FO>
__global__ __launch_bounds__(256) void k_mix(const float* __restrict__ hp,
                                             const float* __restrict__ lin,
                                             const float* __restrict__ hin,
                                             const float* __restrict__ res,
                                             TO* __restrict__ out) {
  int n0 = blockIdx.y * 64;
  int o0 = blockIdx.x * 64;
  int tx = threadIdx.x & 15, ty = threadIdx.x >> 4;
  __shared__ float sA[64][17];
  __shared__ float sB[16][65];
  float acc[4][4] = {};
  for (int k0 = 0; k0 < KC; k0 += 16) {
#pragma unroll
    for (int q = 0; q < 4; q++)
      sA[ty + 16 * q][tx] = hp[(size_t)(n0 + ty + 16 * q) * KC + k0 + tx];
#pragma unroll
    for (int p = 0; p < 4; p++)
      sB[ty][tx + 16 * p] = lin[(size_t)(k0 + ty) * FO + o0 + tx + 16 * p];
    __syncthreads();
#pragma unroll
    for (int k = 0; k < 16; k++) {
      float a[4], b[4];
#pragma unroll
      for (int q = 0; q < 4; q++) a[q] = sA[ty + 16 * q][k];
#pragma unroll
      for (int p = 0; p < 4; p++) b[p] = sB[k][tx + 16 * p];
#pragma unroll
      for (int q = 0; q < 4; q++)
#pragma unroll
        for (int p = 0; p < 4; p++) acc[q][p] += a[q] * b[p];
    }
    __syncthreads();
  }
#pragma unroll
  for (int q = 0; q < 4; q++)
#pragma unroll
    for (int p = 0; p < 4; p++) {
      float v = acc[q][p];
      acc[q][p] = v > 0.f ? v : __expf(v) - 1.f;   // elu on hp@lin
    }
  for (int k0 = 0; k0 < KR; k0 += 16) {
#pragma unroll
    for (int q = 0; q < 4; q++)
      sA[ty + 16 * q][tx] = hin[(size_t)(n0 + ty + 16 * q) * KR + k0 + tx];
#pragma unroll
    for (int p = 0; p < 4; p++)
      sB[ty][tx + 16 * p] = res[(size_t)(k0 + ty) * FO + o0 + tx + 16 * p];
    __syncthreads();
#pragma unroll
    for (int k = 0; k < 16; k++) {
      float a[4], b[4];
#pragma unroll
      for (int q = 0; q < 4; q++) a[q] = sA[ty + 16 * q][k];
#pragma unroll
      for (int p = 0; p < 4; p++) b[p] = sB[k][tx + 16 * p];
#pragma unroll
      for (int q = 0; q < 4; q++)
#pragma unroll
        for (int p = 0; p < 4; p++) acc[q][p] += a[q] * b[p];
    }
    __syncthreads();
  }
#pragma unroll
  for (int q = 0; q < 4; q++)
#pragma unroll
    for (int p = 0; p < 4; p++) {
      float v = acc[q][p];
      v = v > 0.f ? v : 0.f;                       // relu (relu(relu(x))==relu(x))
      storef(&out[(size_t)(n0 + ty + 16 * q) * FO + o0 + tx + 16 * p], v);
    }
}

// ---------------------------------------------------------------- launcher
extern "C" void kernel_launch(void* const* d_in, const int* in_sizes, int n_in,
                              void* d_out, int out_size, void* d_ws, size_t ws_size,
                              hipStream_t stream) {
  const float* x    = (const float*)d_in[0];
  const int*   adj  = (const int*)d_in[1];
  const float* W1   = (const float*)d_in[2];
  const float* a1s  = (const float*)d_in[3];
  const float* a1d  = (const float*)d_in[4];
  const float* lin1 = (const float*)d_in[5];
  const float* res1 = (const float*)d_in[6];
  const float* W2   = (const float*)d_in[7];
  const float* a2s  = (const float*)d_in[8];
  const float* a2d  = (const float*)d_in[9];
  const float* lin2 = (const float*)d_in[10];
  const float* res2 = (const float*)d_in[11];
  float* out = (float*)d_out;   // reference output dtype is float32

  char* p = (char*)d_ws;
  auto alloc = [&](size_t bytes) { void* r = (void*)p; p += (bytes + 255) & ~(size_t)255; return r; };
  uint32_t* bits = (uint32_t*)alloc((size_t)N * NW * 4);
  float* Wh1  = (float*)alloc((size_t)HEADS * N * F1 * 4);
  float* src1 = (float*)alloc((size_t)HEADS * N * 4);
  float* dst1 = (float*)alloc((size_t)HEADS * N * 4);
  float* hp1  = (float*)alloc((size_t)N * HEADS * F1 * 4);
  float* h1   = (float*)alloc((size_t)N * F1 * 4);
  float* Wh2  = (float*)alloc((size_t)HEADS * N * F2 * 4);
  float* src2 = (float*)alloc((size_t)HEADS * N * 4);
  float* dst2 = (float*)alloc((size_t)HEADS * N * 4);
  float* hp2  = (float*)alloc((size_t)N * HEADS * F2 * 4);

  k_pack_adj<<<dim3(N * N / 256), dim3(256), 0, stream>>>(adj, bits);

  // layer 1
  k_whead<D0, F1><<<dim3(F1 / 64, N / 64, HEADS), dim3(256), 0, stream>>>(x, W1, Wh1);
  k_srcdst<F1><<<dim3(HEADS * N / 4), dim3(256), 0, stream>>>(Wh1, a1s, a1d, src1, dst1);
  k_attn<F1><<<dim3(N / 64, HEADS), dim3(256), 0, stream>>>(Wh1, src1, dst1, bits, hp1);
  k_mix<float, HEADS * F1, D0, F1>
      <<<dim3(F1 / 64, N / 64), dim3(256), 0, stream>>>(hp1, lin1, x, res1, h1);

  // layer 2
  k_whead<F1, F2><<<dim3(F2 / 64, N / 64, HEADS), dim3(256), 0, stream>>>(h1, W2, Wh2);
  k_srcdst<F2><<<dim3(HEADS * N / 4), dim3(256), 0, stream>>>(Wh2, a2s, a2d, src2, dst2);
  k_attn<F2><<<dim3(N / 64, HEADS), dim3(256), 0, stream>>>(Wh2, src2, dst2, bits, hp2);
  k_mix<float, HEADS * F2, F1, F2>
      <<<dim3(F2 / 64, N / 64), dim3(256), 0, stream>>>(hp2, lin2, h1, res2, out);
}

// Round 4
// 476.221 us; speedup vs baseline: 1.7967x; 1.7967x over previous
//
#include <hip/hip_runtime.h>
#include <hip/hip_bf16.h>
#include <stdint.h>

using bf16 = __hip_bfloat16;
typedef short short8 __attribute__((ext_vector_type(8)));
typedef float f32x4 __attribute__((ext_vector_type(4)));

constexpr int N = 3072;
constexpr int D0 = 256;
constexpr int F1 = 128;
constexpr int F2 = 64;
constexpr int HEADS = 4;
constexpr int NW = N / 32;          // mask words per row
constexpr float CSHIFT = 20.0f;     // fixed softmax shift (softmax is shift-invariant)

// ---------------------------------------------------------------- pack adj
__global__ __launch_bounds__(256) void k_pack_adj(const int* __restrict__ adj,
                                                  uint32_t* __restrict__ bits) {
  int idx = blockIdx.x * 256 + threadIdx.x;           // over N*N, j fastest
  unsigned long long m = __ballot(adj[idx] > 0);
  if ((threadIdx.x & 63) == 0) {
    bits[idx >> 5]       = (uint32_t)m;
    bits[(idx >> 5) + 1] = (uint32_t)(m >> 32);
  }
}

// ------------------------------------------------- per-head projection GEMM
// Wh[h][n][o] = sum_k A[n][k] * W[h][k][o]  (fp32) ; also WhT[h][o][n] (bf16)
template <int FIN, int FOUT>
__global__ __launch_bounds__(256) void k_whead(const float* __restrict__ A,
                                               const float* __restrict__ W,
                                               float* __restrict__ Wh,
                                               bf16* __restrict__ WhT) {
  int h  = blockIdx.z;
  int n0 = blockIdx.y * 64;
  int o0 = blockIdx.x * 64;
  int tx = threadIdx.x & 15, ty = threadIdx.x >> 4;
  __shared__ float sA[64][17];
  __shared__ float sB[16][65];
  __shared__ __align__(16) bf16 sT[64][72];
  const float* Wp = W + (size_t)h * FIN * FOUT;
  float acc[4][4] = {};
  for (int k0 = 0; k0 < FIN; k0 += 16) {
#pragma unroll
    for (int q = 0; q < 4; q++)
      sA[ty + 16 * q][tx] = A[(size_t)(n0 + ty + 16 * q) * FIN + k0 + tx];
#pragma unroll
    for (int p = 0; p < 4; p++)
      sB[ty][tx + 16 * p] = Wp[(size_t)(k0 + ty) * FOUT + o0 + tx + 16 * p];
    __syncthreads();
#pragma unroll
    for (int k = 0; k < 16; k++) {
      float a[4], b[4];
#pragma unroll
      for (int q = 0; q < 4; q++) a[q] = sA[ty + 16 * q][k];
#pragma unroll
      for (int p = 0; p < 4; p++) b[p] = sB[k][tx + 16 * p];
#pragma unroll
      for (int q = 0; q < 4; q++)
#pragma unroll
        for (int p = 0; p < 4; p++) acc[q][p] += a[q] * b[p];
    }
    __syncthreads();
  }
#pragma unroll
  for (int q = 0; q < 4; q++)
#pragma unroll
    for (int p = 0; p < 4; p++) {
      Wh[((size_t)h * N + n0 + ty + 16 * q) * FOUT + o0 + tx + 16 * p] = acc[q][p];
      sT[tx + 16 * p][ty + 16 * q] = __float2bfloat16(acc[q][p]);   // transpose in LDS
    }
  __syncthreads();
  if (threadIdx.x < 64) {
    int o = threadIdx.x;
    bf16* dp = WhT + ((size_t)(h * FOUT + o0 + o)) * N + n0;
#pragma unroll
    for (int kk = 0; kk < 8; kk++)
      *(short8*)(dp + kk * 8) = *(const short8*)(&sT[o][kk * 8]);
  }
}

// ---------------------------------------------------------- src/dst vectors
template <int F>
__global__ __launch_bounds__(256) void k_srcdst(const float* __restrict__ Wh,
                                                const float* __restrict__ as_,
                                                const float* __restrict__ ad_,
                                                float* __restrict__ src,
                                                float* __restrict__ dst) {
  int hn   = blockIdx.x * 4 + (threadIdx.x >> 6);
  int lane = threadIdx.x & 63;
  int h    = hn / N;
  const float* rowp = Wh + (size_t)hn * F;
  float s = 0.f, d = 0.f;
  for (int o = lane; o < F; o += 64) {
    float w = rowp[o];
    s += w * as_[h * F + o];
    d += w * ad_[h * F + o];
  }
#pragma unroll
  for (int off = 32; off; off >>= 1) {
    s += __shfl_down(s, off);
    d += __shfl_down(d, off);
  }
  if (lane == 0) { src[hn] = s; dst[hn] = d; }
}

// ------------------------------------------------- logits: P = exp(l - C), masked
// one wave per (head,row); also writes row sum s
__global__ __launch_bounds__(256) void k_logits(const float* __restrict__ src,
                                                const float* __restrict__ dst,
                                                const uint32_t* __restrict__ bits,
                                                bf16* __restrict__ P,
                                                float* __restrict__ s) {
  int h    = blockIdx.y;
  int wid  = threadIdx.x >> 6, lane = threadIdx.x & 63;
  int row  = blockIdx.x * 4 + wid;
  float srcr = src[h * N + row];
  const float* dh = dst + h * N;
  const uint32_t* br = bits + (size_t)row * NW;
  bf16* Pr = P + (size_t)h * N * N + (size_t)row * N;
  float sum = 0.f;
  for (int it = 0; it < N / 64; it++) {
    int j = it * 64 + lane;
    float t = srcr + dh[j];
    t = t > 0.f ? t : 0.2f * t;
    uint32_t w = br[j >> 5];
    float p = ((w >> (j & 31)) & 1u) ? __expf(t - CSHIFT) : 0.f;
    Pr[j] = __float2bfloat16(p);
    sum += p;
  }
#pragma unroll
  for (int off = 32; off; off >>= 1) sum += __shfl_down(sum, off);
  if (lane == 0) s[h * N + row] = sum;
}

// ------------------------------------------------- PV GEMM: hp = elu(P@Wh / s)
// block = 4 waves, each wave a K-quarter; MFMA 16x16x32 bf16, frags direct from global
template <int F>
__global__ __launch_bounds__(256) void k_pv(const bf16* __restrict__ P,
                                            const bf16* __restrict__ WhT,
                                            const float* __restrict__ s,
                                            float* __restrict__ hp) {
  constexpr int CT = F / 16;          // col tiles per wave (8 or 4)
  constexpr int CTN = CT / 4;         // col tiles per wave in epilogue
  int h   = blockIdx.y;
  int i0  = blockIdx.x * 16;
  int wid = threadIdx.x >> 6, lane = threadIdx.x & 63;
  int l15 = lane & 15, q = lane >> 4;

  const bf16* aP = P + (size_t)h * N * N + (size_t)(i0 + l15) * N + q * 8 + wid * (N / 4);
  const bf16* bP = WhT + (size_t)(h * F + l15) * N + q * 8 + wid * (N / 4);

  f32x4 acc[CT];
#pragma unroll
  for (int ct = 0; ct < CT; ct++)
#pragma unroll
    for (int r = 0; r < 4; r++) acc[ct][r] = 0.f;

  for (int ks = 0; ks < N / 128; ks++) {       // 24 K-steps of 32 in this wave's quarter
    short8 a = *(const short8*)(aP + ks * 32);
#pragma unroll
    for (int ct = 0; ct < CT; ct++) {
      short8 b = *(const short8*)(bP + (size_t)ct * 16 * N + ks * 32);
      acc[ct] = __builtin_amdgcn_mfma_f32_16x16x32_bf16(a, b, acc[ct], 0, 0, 0);
    }
  }

  __shared__ float red[4][64][CT * 4 + 1];
#pragma unroll
  for (int ct = 0; ct < CT; ct++)
#pragma unroll
    for (int r = 0; r < 4; r++) red[wid][lane][ct * 4 + r] = acc[ct][r];
  __syncthreads();

#pragma unroll
  for (int cc = 0; cc < CTN; cc++) {
    int ct = wid * CTN + cc;
#pragma unroll
    for (int r = 0; r < 4; r++) {
      float v = red[0][lane][ct * 4 + r] + red[1][lane][ct * 4 + r] +
                red[2][lane][ct * 4 + r] + red[3][lane][ct * 4 + r];
      int gi = i0 + q * 4 + r;
      v /= s[h * N + gi];
      v = v > 0.f ? v : __expf(v) - 1.f;       // elu
      hp[(size_t)gi * (HEADS * F) + h * F + ct * 16 + l15] = v;
    }
  }
}

// ------------------------------------- hp@lin (elu) + hin@res, relu -> out
template <int KC, int KR, int FO>
__global__ __launch_bounds__(256) void k_mix(const float* __restrict__ hp,
                                             const float* __restrict__ lin,
                                             const float* __restrict__ hin,
                                             const float* __restrict__ res,
                                             float* __restrict__ out) {
  int n0 = blockIdx.y * 64;
  int o0 = blockIdx.x * 64;
  int tx = threadIdx.x & 15, ty = threadIdx.x >> 4;
  __shared__ float sA[64][17];
  __shared__ float sB[16][65];
  float acc[4][4] = {};
  for (int k0 = 0; k0 < KC; k0 += 16) {
#pragma unroll
    for (int q = 0; q < 4; q++)
      sA[ty + 16 * q][tx] = hp[(size_t)(n0 + ty + 16 * q) * KC + k0 + tx];
#pragma unroll
    for (int p = 0; p < 4; p++)
      sB[ty][tx + 16 * p] = lin[(size_t)(k0 + ty) * FO + o0 + tx + 16 * p];
    __syncthreads();
#pragma unroll
    for (int k = 0; k < 16; k++) {
      float a[4], b[4];
#pragma unroll
      for (int q = 0; q < 4; q++) a[q] = sA[ty + 16 * q][k];
#pragma unroll
      for (int p = 0; p < 4; p++) b[p] = sB[k][tx + 16 * p];
#pragma unroll
      for (int q = 0; q < 4; q++)
#pragma unroll
        for (int p = 0; p < 4; p++) acc[q][p] += a[q] * b[p];
    }
    __syncthreads();
  }
#pragma unroll
  for (int q = 0; q < 4; q++)
#pragma unroll
    for (int p = 0; p < 4; p++) {
      float v = acc[q][p];
      acc[q][p] = v > 0.f ? v : __expf(v) - 1.f;   // elu on hp@lin
    }
  for (int k0 = 0; k0 < KR; k0 += 16) {
#pragma unroll
    for (int q = 0; q < 4; q++)
      sA[ty + 16 * q][tx] = hin[(size_t)(n0 + ty + 16 * q) * KR + k0 + tx];
#pragma unroll
    for (int p = 0; p < 4; p++)
      sB[ty][tx + 16 * p] = res[(size_t)(k0 + ty) * FO + o0 + tx + 16 * p];
    __syncthreads();
#pragma unroll
    for (int k = 0; k < 16; k++) {
      float a[4], b[4];
#pragma unroll
      for (int q = 0; q < 4; q++) a[q] = sA[ty + 16 * q][k];
#pragma unroll
      for (int p = 0; p < 4; p++) b[p] = sB[k][tx + 16 * p];
#pragma unroll
      for (int q = 0; q < 4; q++)
#pragma unroll
        for (int p = 0; p < 4; p++) acc[q][p] += a[q] * b[p];
    }
    __syncthreads();
  }
#pragma unroll
  for (int q = 0; q < 4; q++)
#pragma unroll
    for (int p = 0; p < 4; p++) {
      float v = acc[q][p];
      out[(size_t)(n0 + ty + 16 * q) * FO + o0 + tx + 16 * p] = v > 0.f ? v : 0.f;
    }
}

// ---------------------------------------------------------------- launcher
extern "C" void kernel_launch(void* const* d_in, const int* in_sizes, int n_in,
                              void* d_out, int out_size, void* d_ws, size_t ws_size,
                              hipStream_t stream) {
  const float* x    = (const float*)d_in[0];
  const int*   adj  = (const int*)d_in[1];
  const float* W1   = (const float*)d_in[2];
  const float* a1s  = (const float*)d_in[3];
  const float* a1d  = (const float*)d_in[4];
  const float* lin1 = (const float*)d_in[5];
  const float* res1 = (const float*)d_in[6];
  const float* W2   = (const float*)d_in[7];
  const float* a2s  = (const float*)d_in[8];
  const float* a2d  = (const float*)d_in[9];
  const float* lin2 = (const float*)d_in[10];
  const float* res2 = (const float*)d_in[11];
  float* out = (float*)d_out;

  char* p = (char*)d_ws;
  auto alloc = [&](size_t bytes) { void* r = (void*)p; p += (bytes + 255) & ~(size_t)255; return r; };
  uint32_t* bits = (uint32_t*)alloc((size_t)N * NW * 4);
  float* Wh1  = (float*)alloc((size_t)HEADS * N * F1 * 4);
  bf16*  WhT1 = (bf16*)alloc((size_t)HEADS * F1 * N * 2);
  float* src1 = (float*)alloc((size_t)HEADS * N * 4);
  float* dst1 = (float*)alloc((size_t)HEADS * N * 4);
  float* s1   = (float*)alloc((size_t)HEADS * N * 4);
  float* hp1  = (float*)alloc((size_t)N * HEADS * F1 * 4);
  float* h1   = (float*)alloc((size_t)N * F1 * 4);
  float* Wh2  = (float*)alloc((size_t)HEADS * N * F2 * 4);
  bf16*  WhT2 = (bf16*)alloc((size_t)HEADS * F2 * N * 2);
  float* src2 = (float*)alloc((size_t)HEADS * N * 4);
  float* dst2 = (float*)alloc((size_t)HEADS * N * 4);
  float* s2   = (float*)alloc((size_t)HEADS * N * 4);
  float* hp2  = (float*)alloc((size_t)N * HEADS * F2 * 4);
  bf16*  P    = (bf16*)alloc((size_t)HEADS * N * N * 2);   // reused by both layers

  k_pack_adj<<<dim3(N * N / 256), dim3(256), 0, stream>>>(adj, bits);

  // layer 1
  k_whead<D0, F1><<<dim3(F1 / 64, N / 64, HEADS), dim3(256), 0, stream>>>(x, W1, Wh1, WhT1);
  k_srcdst<F1><<<dim3(HEADS * N / 4), dim3(256), 0, stream>>>(Wh1, a1s, a1d, src1, dst1);
  k_logits<<<dim3(N / 4, HEADS), dim3(256), 0, stream>>>(src1, dst1, bits, P, s1);
  k_pv<F1><<<dim3(N / 16, HEADS), dim3(256), 0, stream>>>(P, WhT1, s1, hp1);
  k_mix<HEADS * F1, D0, F1><<<dim3(F1 / 64, N / 64), dim3(256), 0, stream>>>(hp1, lin1, x, res1, h1);

  // layer 2
  k_whead<F1, F2><<<dim3(F2 / 64, N / 64, HEADS), dim3(256), 0, stream>>>(h1, W2, Wh2, WhT2);
  k_srcdst<F2><<<dim3(HEADS * N / 4), dim3(256), 0, stream>>>(Wh2, a2s, a2d, src2, dst2);
  k_logits<<<dim3(N / 4, HEADS), dim3(256), 0, stream>>>(src2, dst2, bits, P, s2);
  k_pv<F2><<<dim3(N / 16, HEADS), dim3(256), 0, stream>>>(P, WhT2, s2, hp2);
  k_mix<HEADS * F2, F1, F2><<<dim3(F2 / 64, N / 64), dim3(256), 0, stream>>>(hp2, lin2, h1, res2, out);
}

// Round 5
// 373.012 us; speedup vs baseline: 2.2938x; 1.2767x over previous
//
#include <hip/hip_runtime.h>
#include <hip/hip_bf16.h>
#include <stdint.h>

using bf16 = __hip_bfloat16;
typedef short short8 __attribute__((ext_vector_type(8)));
typedef short short4v __attribute__((ext_vector_type(4)));
typedef float f32x4 __attribute__((ext_vector_type(4)));

constexpr int N = 3072;
constexpr int D0 = 256;
constexpr int F1 = 128;
constexpr int F2 = 64;
constexpr int HEADS = 4;
constexpr int NW = N / 32;
constexpr float CSHIFT = 20.0f;   // softmax shift-invariance: fixed shift, no max pass

#define DI __device__ __forceinline__
DI short f2bs(float v) { bf16 b = __float2bfloat16(v); return *(short*)&b; }

// ---------------------------------------------------------------- pack adj
__global__ __launch_bounds__(256) void k_pack_adj(const int* __restrict__ adj,
                                                  uint32_t* __restrict__ bits) {
  int idx = blockIdx.x * 256 + threadIdx.x;
  unsigned long long m = __ballot(adj[idx] > 0);
  if ((threadIdx.x & 63) == 0) {
    bits[idx >> 5]       = (uint32_t)m;
    bits[(idx >> 5) + 1] = (uint32_t)(m >> 32);
  }
}

// ------------------------------------------------- convert params + x to bf16
// transposed layouts [col][k] for MFMA B-operands
__global__ __launch_bounds__(256) void k_cvt(const float* __restrict__ x,
                                             const float* __restrict__ W1,
                                             const float* __restrict__ lin1,
                                             const float* __restrict__ res1,
                                             const float* __restrict__ W2,
                                             const float* __restrict__ lin2,
                                             const float* __restrict__ res2,
                                             bf16* __restrict__ xb,
                                             bf16* __restrict__ W1T,
                                             bf16* __restrict__ lin1T,
                                             bf16* __restrict__ res1T,
                                             bf16* __restrict__ W2T,
                                             bf16* __restrict__ lin2T,
                                             bf16* __restrict__ res2T) {
  int t = blockIdx.y;
  int i = blockIdx.x * 256 + threadIdx.x;
  switch (t) {
    case 0:  // x [3072][256] straight cast
      if (i < N * D0) xb[i] = __float2bfloat16(x[i]);
      break;
    case 1:  // W1T[(h*128+o)][k<256] = W1[(h*256+k)*128+o]
      if (i < HEADS * F1 * D0) { int k = i & 255; int ho = i >> 8; int h = ho >> 7, o = ho & 127;
        W1T[i] = __float2bfloat16(W1[((size_t)h * D0 + k) * F1 + o]); }
      break;
    case 2:  // lin1T[o<128][k<512] = lin1[k*128+o]
      if (i < F1 * HEADS * F1) { int k = i & 511; int o = i >> 9;
        lin1T[i] = __float2bfloat16(lin1[k * F1 + o]); }
      break;
    case 3:  // res1T[o<128][k<256] = res1[k*128+o]
      if (i < F1 * D0) { int k = i & 255; int o = i >> 8;
        res1T[i] = __float2bfloat16(res1[k * F1 + o]); }
      break;
    case 4:  // W2T[(h*64+o)][k<128] = W2[(h*128+k)*64+o]
      if (i < HEADS * F2 * F1) { int k = i & 127; int ho = i >> 7; int h = ho >> 6, o = ho & 63;
        W2T[i] = __float2bfloat16(W2[((size_t)h * F1 + k) * F2 + o]); }
      break;
    case 5:  // lin2T[o<64][k<256] = lin2[k*64+o]
      if (i < F2 * HEADS * F2) { int k = i & 255; int o = i >> 8;
        lin2T[i] = __float2bfloat16(lin2[k * F2 + o]); }
      break;
    case 6:  // res2T[o<64][k<128] = res2[k*64+o]
      if (i < F2 * F1) { int k = i & 127; int o = i >> 7;
        res2T[i] = __float2bfloat16(res2[k * F2 + o]); }
      break;
  }
}

// ------------------------------------------------- projection GEMM (MFMA)
// WhT[col][row] = sum_k A[row][k] * BT[col][k]; A [3072][K] bf16, BT [NOUT][K] bf16
template <int K, int NOUT>
__global__ __launch_bounds__(256) void k_whead_mfma(const bf16* __restrict__ A,
                                                    const bf16* __restrict__ BT,
                                                    bf16* __restrict__ WhT) {
  int n0 = blockIdx.x * 64;
  int c0 = blockIdx.y * 64;
  int wid = threadIdx.x >> 6, lane = threadIdx.x & 63;
  int l15 = lane & 15, q = lane >> 4;
  int row0 = n0 + wid * 16;
  const bf16* aP = A + (size_t)(row0 + l15) * K + q * 8;
  f32x4 acc[4];
#pragma unroll
  for (int ct = 0; ct < 4; ct++)
#pragma unroll
    for (int r = 0; r < 4; r++) acc[ct][r] = 0.f;
  for (int ks = 0; ks < K / 32; ks++) {
    short8 a = *(const short8*)(aP + ks * 32);
#pragma unroll
    for (int ct = 0; ct < 4; ct++) {
      short8 b = *(const short8*)(BT + (size_t)(c0 + ct * 16 + l15) * K + q * 8 + ks * 32);
      acc[ct] = __builtin_amdgcn_mfma_f32_16x16x32_bf16(a, b, acc[ct], 0, 0, 0);
    }
  }
#pragma unroll
  for (int ct = 0; ct < 4; ct++) {
    int col = c0 + ct * 16 + l15;
    short4v w;
#pragma unroll
    for (int r = 0; r < 4; r++) w[r] = f2bs(acc[ct][r]);
    *(short4v*)(WhT + (size_t)col * N + row0 + q * 4) = w;   // 4 consecutive rows
  }
}

// ---------------------------------------------------------- src/dst from WhT
template <int F>
__global__ __launch_bounds__(256) void k_srcdst(const bf16* __restrict__ WhT,
                                                const float* __restrict__ as_,
                                                const float* __restrict__ ad_,
                                                float* __restrict__ src,
                                                float* __restrict__ dst) {
  int h = blockIdx.y;
  int n = blockIdx.x * 256 + threadIdx.x;
  float s = 0.f, d = 0.f;
  for (int o = 0; o < F; o++) {
    float w = __bfloat162float(WhT[(size_t)(h * F + o) * N + n]);
    s += w * as_[h * F + o];
    d += w * ad_[h * F + o];
  }
  src[h * N + n] = s;
  dst[h * N + n] = d;
}

// ------------------------------------------------- logits: P = exp(l - C), masked
__global__ __launch_bounds__(256) void k_logits(const float* __restrict__ src,
                                                const float* __restrict__ dst,
                                                const uint32_t* __restrict__ bits,
                                                bf16* __restrict__ P,
                                                float* __restrict__ s) {
  int h   = blockIdx.y;
  int wid = threadIdx.x >> 6, lane = threadIdx.x & 63;
  int row = blockIdx.x * 4 + wid;
  float srcr = src[h * N + row];
  const float* dh = dst + h * N;
  const uint32_t* br = bits + (size_t)row * NW;
  bf16* Pr = P + (size_t)h * N * N + (size_t)row * N;
  float sum = 0.f;
  for (int it = 0; it < N / 64; it++) {
    int j = it * 64 + lane;
    float t = srcr + dh[j];
    t = t > 0.f ? t : 0.2f * t;
    uint32_t w = br[j >> 5];
    float p = ((w >> (j & 31)) & 1u) ? __expf(t - CSHIFT) : 0.f;
    Pr[j] = __float2bfloat16(p);
    sum += p;
  }
#pragma unroll
  for (int off = 32; off; off >>= 1) sum += __shfl_down(sum, off);
  if (lane == 0) s[h * N + row] = sum;
}

// ------------------------------------------------- PV GEMM: hp = elu(P@Wh / s), bf16 out
template <int F>
__global__ __launch_bounds__(256) void k_pv(const bf16* __restrict__ P,
                                            const bf16* __restrict__ WhT,
                                            const float* __restrict__ s,
                                            bf16* __restrict__ hp) {
  constexpr int CT = F / 16;
  constexpr int CTN = CT / 4;
  int h   = blockIdx.y;
  int i0  = blockIdx.x * 16;
  int wid = threadIdx.x >> 6, lane = threadIdx.x & 63;
  int l15 = lane & 15, q = lane >> 4;

  const bf16* aP = P + (size_t)h * N * N + (size_t)(i0 + l15) * N + q * 8 + wid * (N / 4);
  const bf16* bP = WhT + (size_t)(h * F + l15) * N + q * 8 + wid * (N / 4);

  f32x4 acc[CT];
#pragma unroll
  for (int ct = 0; ct < CT; ct++)
#pragma unroll
    for (int r = 0; r < 4; r++) acc[ct][r] = 0.f;

  for (int ks = 0; ks < N / 128; ks++) {
    short8 a = *(const short8*)(aP + ks * 32);
#pragma unroll
    for (int ct = 0; ct < CT; ct++) {
      short8 b = *(const short8*)(bP + (size_t)ct * 16 * N + ks * 32);
      acc[ct] = __builtin_amdgcn_mfma_f32_16x16x32_bf16(a, b, acc[ct], 0, 0, 0);
    }
  }

  __shared__ float red[4][64][CT * 4 + 1];
#pragma unroll
  for (int ct = 0; ct < CT; ct++)
#pragma unroll
    for (int r = 0; r < 4; r++) red[wid][lane][ct * 4 + r] = acc[ct][r];
  __syncthreads();

#pragma unroll
  for (int cc = 0; cc < CTN; cc++) {
    int ct = wid * CTN + cc;
#pragma unroll
    for (int r = 0; r < 4; r++) {
      float v = red[0][lane][ct * 4 + r] + red[1][lane][ct * 4 + r] +
                red[2][lane][ct * 4 + r] + red[3][lane][ct * 4 + r];
      int gi = i0 + q * 4 + r;
      v /= s[h * N + gi];
      v = v > 0.f ? v : __expf(v) - 1.f;       // elu
      hp[(size_t)gi * (HEADS * F) + h * F + ct * 16 + l15] = __float2bfloat16(v);
    }
  }
}

// ------------------------------ mix GEMM (MFMA): out = relu(elu(A1@B1) + A2@B2)
// A1 [3072][K1] bf16 rm, B1T [NOUT][K1], A2 [3072][K2], B2T [NOUT][K2]
template <int K1, int K2, int NOUT, bool F32OUT>
__global__ __launch_bounds__(256) void k_mix_mfma(const bf16* __restrict__ A1,
                                                  const bf16* __restrict__ B1T,
                                                  const bf16* __restrict__ A2,
                                                  const bf16* __restrict__ B2T,
                                                  void* __restrict__ outv) {
  int n0 = blockIdx.x * 64;
  int c0 = blockIdx.y * 64;
  int wid = threadIdx.x >> 6, lane = threadIdx.x & 63;
  int l15 = lane & 15, q = lane >> 4;
  int row0 = n0 + wid * 16;

  f32x4 acc1[4], acc2[4];
#pragma unroll
  for (int ct = 0; ct < 4; ct++)
#pragma unroll
    for (int r = 0; r < 4; r++) { acc1[ct][r] = 0.f; acc2[ct][r] = 0.f; }

  const bf16* a1P = A1 + (size_t)(row0 + l15) * K1 + q * 8;
  for (int ks = 0; ks < K1 / 32; ks++) {
    short8 a = *(const short8*)(a1P + ks * 32);
#pragma unroll
    for (int ct = 0; ct < 4; ct++) {
      short8 b = *(const short8*)(B1T + (size_t)(c0 + ct * 16 + l15) * K1 + q * 8 + ks * 32);
      acc1[ct] = __builtin_amdgcn_mfma_f32_16x16x32_bf16(a, b, acc1[ct], 0, 0, 0);
    }
  }
  const bf16* a2P = A2 + (size_t)(row0 + l15) * K2 + q * 8;
  for (int ks = 0; ks < K2 / 32; ks++) {
    short8 a = *(const short8*)(a2P + ks * 32);
#pragma unroll
    for (int ct = 0; ct < 4; ct++) {
      short8 b = *(const short8*)(B2T + (size_t)(c0 + ct * 16 + l15) * K2 + q * 8 + ks * 32);
      acc2[ct] = __builtin_amdgcn_mfma_f32_16x16x32_bf16(a, b, acc2[ct], 0, 0, 0);
    }
  }

#pragma unroll
  for (int ct = 0; ct < 4; ct++) {
    int col = c0 + ct * 16 + l15;
#pragma unroll
    for (int r = 0; r < 4; r++) {
      float v = acc1[ct][r];
      v = v > 0.f ? v : __expf(v) - 1.f;         // elu on A1@B1
      v += acc2[ct][r];
      v = v > 0.f ? v : 0.f;                     // relu
      int row = row0 + q * 4 + r;
      if (F32OUT) ((float*)outv)[(size_t)row * NOUT + col] = v;
      else        ((bf16*)outv)[(size_t)row * NOUT + col] = __float2bfloat16(v);
    }
  }
}

// ---------------------------------------------------------------- launcher
extern "C" void kernel_launch(void* const* d_in, const int* in_sizes, int n_in,
                              void* d_out, int out_size, void* d_ws, size_t ws_size,
                              hipStream_t stream) {
  const float* x    = (const float*)d_in[0];
  const int*   adj  = (const int*)d_in[1];
  const float* W1   = (const float*)d_in[2];
  const float* a1s  = (const float*)d_in[3];
  const float* a1d  = (const float*)d_in[4];
  const float* lin1 = (const float*)d_in[5];
  const float* res1 = (const float*)d_in[6];
  const float* W2   = (const float*)d_in[7];
  const float* a2s  = (const float*)d_in[8];
  const float* a2d  = (const float*)d_in[9];
  const float* lin2 = (const float*)d_in[10];
  const float* res2 = (const float*)d_in[11];
  float* out = (float*)d_out;

  char* p = (char*)d_ws;
  auto alloc = [&](size_t bytes) { void* r = (void*)p; p += (bytes + 255) & ~(size_t)255; return r; };
  uint32_t* bits = (uint32_t*)alloc((size_t)N * NW * 4);
  bf16* xb    = (bf16*)alloc((size_t)N * D0 * 2);
  bf16* W1T   = (bf16*)alloc((size_t)HEADS * F1 * D0 * 2);
  bf16* lin1T = (bf16*)alloc((size_t)F1 * HEADS * F1 * 2);
  bf16* res1T = (bf16*)alloc((size_t)F1 * D0 * 2);
  bf16* W2T   = (bf16*)alloc((size_t)HEADS * F2 * F1 * 2);
  bf16* lin2T = (bf16*)alloc((size_t)F2 * HEADS * F2 * 2);
  bf16* res2T = (bf16*)alloc((size_t)F2 * F1 * 2);
  bf16* WhT1  = (bf16*)alloc((size_t)HEADS * F1 * N * 2);
  bf16* WhT2  = (bf16*)alloc((size_t)HEADS * F2 * N * 2);
  float* src1 = (float*)alloc((size_t)HEADS * N * 4);
  float* dst1 = (float*)alloc((size_t)HEADS * N * 4);
  float* s1   = (float*)alloc((size_t)HEADS * N * 4);
  float* src2 = (float*)alloc((size_t)HEADS * N * 4);
  float* dst2 = (float*)alloc((size_t)HEADS * N * 4);
  float* s2   = (float*)alloc((size_t)HEADS * N * 4);
  bf16* hp1   = (bf16*)alloc((size_t)N * HEADS * F1 * 2);
  bf16* hp2   = (bf16*)alloc((size_t)N * HEADS * F2 * 2);
  bf16* h1b   = (bf16*)alloc((size_t)N * F1 * 2);
  bf16* P     = (bf16*)alloc((size_t)HEADS * N * N * 2);

  k_pack_adj<<<dim3(N * N / 256), dim3(256), 0, stream>>>(adj, bits);
  k_cvt<<<dim3(N * D0 / 256, 7), dim3(256), 0, stream>>>(x, W1, lin1, res1, W2, lin2, res2,
                                                         xb, W1T, lin1T, res1T, W2T, lin2T, res2T);

  // layer 1
  k_whead_mfma<D0, HEADS * F1><<<dim3(N / 64, HEADS * F1 / 64), dim3(256), 0, stream>>>(xb, W1T, WhT1);
  k_srcdst<F1><<<dim3(N / 256, HEADS), dim3(256), 0, stream>>>(WhT1, a1s, a1d, src1, dst1);
  k_logits<<<dim3(N / 4, HEADS), dim3(256), 0, stream>>>(src1, dst1, bits, P, s1);
  k_pv<F1><<<dim3(N / 16, HEADS), dim3(256), 0, stream>>>(P, WhT1, s1, hp1);
  k_mix_mfma<HEADS * F1, D0, F1, false>
      <<<dim3(N / 64, F1 / 64), dim3(256), 0, stream>>>(hp1, lin1T, xb, res1T, h1b);

  // layer 2
  k_whead_mfma<F1, HEADS * F2><<<dim3(N / 64, HEADS * F2 / 64), dim3(256), 0, stream>>>(h1b, W2T, WhT2);
  k_srcdst<F2><<<dim3(N / 256, HEADS), dim3(256), 0, stream>>>(WhT2, a2s, a2d, src2, dst2);
  k_logits<<<dim3(N / 4, HEADS), dim3(256), 0, stream>>>(src2, dst2, bits, P, s2);
  k_pv<F2><<<dim3(N / 16, HEADS), dim3(256), 0, stream>>>(P, WhT2, s2, hp2);
  k_mix_mfma<HEADS * F2, F1, F2, true>
      <<<dim3(N / 64, F2 / 64), dim3(256), 0, stream>>>(hp2, lin2T, h1b, res2T, out);
}

// Round 6
// 281.328 us; speedup vs baseline: 3.0413x; 1.3259x over previous
//
#include <hip/hip_runtime.h>
#include <hip/hip_bf16.h>
#include <stdint.h>

using bf16 = __hip_bfloat16;
typedef short short8 __attribute__((ext_vector_type(8)));
typedef short short4v __attribute__((ext_vector_type(4)));
typedef float f32x4 __attribute__((ext_vector_type(4)));

constexpr int N = 3072;
constexpr int D0 = 256;
constexpr int F1 = 128;
constexpr int F2 = 64;
constexpr int HEADS = 4;
constexpr int NW = N / 32;
constexpr float CSHIFT = 20.0f;   // softmax shift-invariance: fixed shift, no max pass

#define DI __device__ __forceinline__
DI short f2bs(float v) { bf16 b = __float2bfloat16(v); return *(short*)&b; }

// ---------------------------------------------------------------- pack adj
__global__ __launch_bounds__(256) void k_pack_adj(const int* __restrict__ adj,
                                                  uint32_t* __restrict__ bits) {
  int idx = blockIdx.x * 256 + threadIdx.x;
  unsigned long long m = __ballot(adj[idx] > 0);
  if ((threadIdx.x & 63) == 0) {
    bits[idx >> 5]       = (uint32_t)m;
    bits[(idx >> 5) + 1] = (uint32_t)(m >> 32);
  }
}

// ------------------------------------------------- convert params + x to bf16
__global__ __launch_bounds__(256) void k_cvt(const float* __restrict__ x,
                                             const float* __restrict__ W1,
                                             const float* __restrict__ lin1,
                                             const float* __restrict__ res1,
                                             const float* __restrict__ W2,
                                             const float* __restrict__ lin2,
                                             const float* __restrict__ res2,
                                             bf16* __restrict__ xb,
                                             bf16* __restrict__ W1T,
                                             bf16* __restrict__ lin1T,
                                             bf16* __restrict__ res1T,
                                             bf16* __restrict__ W2T,
                                             bf16* __restrict__ lin2T,
                                             bf16* __restrict__ res2T) {
  int t = blockIdx.y;
  int i = blockIdx.x * 256 + threadIdx.x;
  switch (t) {
    case 0:
      if (i < N * D0) xb[i] = __float2bfloat16(x[i]);
      break;
    case 1:
      if (i < HEADS * F1 * D0) { int k = i & 255; int ho = i >> 8; int h = ho >> 7, o = ho & 127;
        W1T[i] = __float2bfloat16(W1[((size_t)h * D0 + k) * F1 + o]); }
      break;
    case 2:
      if (i < F1 * HEADS * F1) { int k = i & 511; int o = i >> 9;
        lin1T[i] = __float2bfloat16(lin1[k * F1 + o]); }
      break;
    case 3:
      if (i < F1 * D0) { int k = i & 255; int o = i >> 8;
        res1T[i] = __float2bfloat16(res1[k * F1 + o]); }
      break;
    case 4:
      if (i < HEADS * F2 * F1) { int k = i & 127; int ho = i >> 7; int h = ho >> 6, o = ho & 63;
        W2T[i] = __float2bfloat16(W2[((size_t)h * F1 + k) * F2 + o]); }
      break;
    case 5:
      if (i < F2 * HEADS * F2) { int k = i & 255; int o = i >> 8;
        lin2T[i] = __float2bfloat16(lin2[k * F2 + o]); }
      break;
    case 6:
      if (i < F2 * F1) { int k = i & 127; int o = i >> 7;
        res2T[i] = __float2bfloat16(res2[k * F2 + o]); }
      break;
  }
}

// ------------------------------------------------- projection GEMM (MFMA)
// WhT[col][row] = sum_k A[row][k] * BT[col][k]
template <int K, int NOUT>
__global__ __launch_bounds__(256) void k_whead_mfma(const bf16* __restrict__ A,
                                                    const bf16* __restrict__ BT,
                                                    bf16* __restrict__ WhT) {
  int n0 = blockIdx.x * 64;
  int c0 = blockIdx.y * 64;
  int wid = threadIdx.x >> 6, lane = threadIdx.x & 63;
  int l15 = lane & 15, q = lane >> 4;
  int row0 = n0 + wid * 16;
  const bf16* aP = A + (size_t)(row0 + l15) * K + q * 8;
  f32x4 acc[4];
#pragma unroll
  for (int ct = 0; ct < 4; ct++)
#pragma unroll
    for (int r = 0; r < 4; r++) acc[ct][r] = 0.f;
  for (int ks = 0; ks < K / 32; ks++) {
    short8 a = *(const short8*)(aP + ks * 32);
#pragma unroll
    for (int ct = 0; ct < 4; ct++) {
      short8 b = *(const short8*)(BT + (size_t)(c0 + ct * 16 + l15) * K + q * 8 + ks * 32);
      acc[ct] = __builtin_amdgcn_mfma_f32_16x16x32_bf16(a, b, acc[ct], 0, 0, 0);
    }
  }
#pragma unroll
  for (int ct = 0; ct < 4; ct++) {
    int col = c0 + ct * 16 + l15;
    short4v w;
#pragma unroll
    for (int r = 0; r < 4; r++) w[r] = f2bs(acc[ct][r]);
    *(short4v*)(WhT + (size_t)col * N + row0 + q * 4) = w;
  }
}

// ---------------------------------------------------------- src/dst from WhT
template <int F>
__global__ __launch_bounds__(256) void k_srcdst(const bf16* __restrict__ WhT,
                                                const float* __restrict__ as_,
                                                const float* __restrict__ ad_,
                                                float* __restrict__ src,
                                                float* __restrict__ dst) {
  int h = blockIdx.y;
  int n = blockIdx.x * 256 + threadIdx.x;
  float s = 0.f, d = 0.f;
  for (int o = 0; o < F; o++) {
    float w = __bfloat162float(WhT[(size_t)(h * F + o) * N + n]);
    s += w * as_[h * F + o];
    d += w * ad_[h * F + o];
  }
  src[h * N + n] = s;
  dst[h * N + n] = d;
}

// ---------------- fused attention: P generated in registers, MFMA PV, elu
// hp[i][h*F+o] = elu( (sum_j P_ij WhT[o][j]) / sum_j P_ij ),
// P_ij = mask * exp(leakyrelu(src_i + dst_j) - C)
template <int F>
__global__ __launch_bounds__(256) void k_attn_fused(const bf16* __restrict__ WhT,
                                                    const float* __restrict__ src,
                                                    const float* __restrict__ dst,
                                                    const uint32_t* __restrict__ bits,
                                                    bf16* __restrict__ hp) {
  constexpr int CT = F / 16;
  constexpr int CTN = CT / 4;
  constexpr int KS = N / 128;               // 24 K-steps of 32 per wave
  int h   = blockIdx.y;
  int i0  = blockIdx.x * 16;
  int wid = threadIdx.x >> 6, lane = threadIdx.x & 63;
  int l15 = lane & 15, q = lane >> 4;
  int row = i0 + l15;

  __shared__ float sDst[N];                 // 12 KB, broadcast-read
  __shared__ float red[4][64][CT * 4 + 1];
  __shared__ float sSum[4][16];

  for (int t = threadIdx.x; t < N; t += 256) sDst[t] = dst[h * N + t];
  float srcr = src[h * N + row];

  uint32_t wds[KS];                         // prefetch this row's mask words
#pragma unroll
  for (int ks = 0; ks < KS; ks++) wds[ks] = bits[(size_t)row * NW + wid * KS + ks];
  __syncthreads();

  const bf16* bP = WhT + (size_t)(h * F + l15) * N + wid * (N / 4) + q * 8;

  f32x4 acc[CT];
#pragma unroll
  for (int ct = 0; ct < CT; ct++)
#pragma unroll
    for (int r = 0; r < 4; r++) acc[ct][r] = 0.f;
  float rowsum = 0.f;

  for (int ks = 0; ks < KS; ks++) {
    int jb = wid * (N / 4) + ks * 32;
    const f32x4* dp = (const f32x4*)(&sDst[jb + q * 8]);
    f32x4 dlo = dp[0], dhi = dp[1];
    uint32_t myb = (wds[ks] >> (q * 8)) & 0xffu;
    float pv[8];
#pragma unroll
    for (int e = 0; e < 8; e++) {
      float t = srcr + (e < 4 ? dlo[e] : dhi[e - 4]);
      t = t > 0.f ? t : 0.2f * t;
      float pe = ((myb >> e) & 1u) ? __expf(t - CSHIFT) : 0.f;
      rowsum += pe;
      pv[e] = pe;
    }
    short8 a;
#pragma unroll
    for (int e = 0; e < 8; e++) a[e] = f2bs(pv[e]);
#pragma unroll
    for (int ct = 0; ct < CT; ct++) {
      short8 b = *(const short8*)(bP + (size_t)ct * 16 * N + ks * 32);
      acc[ct] = __builtin_amdgcn_mfma_f32_16x16x32_bf16(a, b, acc[ct], 0, 0, 0);
    }
  }

  // wave-local row sums: lanes {l15, l15+16, l15+32, l15+48} hold q-slices
  rowsum += __shfl_xor(rowsum, 16);
  rowsum += __shfl_xor(rowsum, 32);
  if (lane < 16) sSum[wid][lane] = rowsum;

#pragma unroll
  for (int ct = 0; ct < CT; ct++)
#pragma unroll
    for (int r = 0; r < 4; r++) red[wid][lane][ct * 4 + r] = acc[ct][r];
  __syncthreads();

#pragma unroll
  for (int cc = 0; cc < CTN; cc++) {
    int ct = wid * CTN + cc;
#pragma unroll
    for (int r = 0; r < 4; r++) {
      float v = red[0][lane][ct * 4 + r] + red[1][lane][ct * 4 + r] +
                red[2][lane][ct * 4 + r] + red[3][lane][ct * 4 + r];
      int ri = q * 4 + r;
      float stot = sSum[0][ri] + sSum[1][ri] + sSum[2][ri] + sSum[3][ri];
      v /= stot;
      v = v > 0.f ? v : __expf(v) - 1.f;       // elu
      hp[(size_t)(i0 + ri) * (HEADS * F) + h * F + ct * 16 + l15] = __float2bfloat16(v);
    }
  }
}

// ------------------------------ mix GEMM (MFMA): out = relu(elu(A1@B1) + A2@B2)
template <int K1, int K2, int NOUT, bool F32OUT>
__global__ __launch_bounds__(256) void k_mix_mfma(const bf16* __restrict__ A1,
                                                  const bf16* __restrict__ B1T,
                                                  const bf16* __restrict__ A2,
                                                  const bf16* __restrict__ B2T,
                                                  void* __restrict__ outv) {
  int n0 = blockIdx.x * 64;
  int c0 = blockIdx.y * 64;
  int wid = threadIdx.x >> 6, lane = threadIdx.x & 63;
  int l15 = lane & 15, q = lane >> 4;
  int row0 = n0 + wid * 16;

  f32x4 acc1[4], acc2[4];
#pragma unroll
  for (int ct = 0; ct < 4; ct++)
#pragma unroll
    for (int r = 0; r < 4; r++) { acc1[ct][r] = 0.f; acc2[ct][r] = 0.f; }

  const bf16* a1P = A1 + (size_t)(row0 + l15) * K1 + q * 8;
  for (int ks = 0; ks < K1 / 32; ks++) {
    short8 a = *(const short8*)(a1P + ks * 32);
#pragma unroll
    for (int ct = 0; ct < 4; ct++) {
      short8 b = *(const short8*)(B1T + (size_t)(c0 + ct * 16 + l15) * K1 + q * 8 + ks * 32);
      acc1[ct] = __builtin_amdgcn_mfma_f32_16x16x32_bf16(a, b, acc1[ct], 0, 0, 0);
    }
  }
  const bf16* a2P = A2 + (size_t)(row0 + l15) * K2 + q * 8;
  for (int ks = 0; ks < K2 / 32; ks++) {
    short8 a = *(const short8*)(a2P + ks * 32);
#pragma unroll
    for (int ct = 0; ct < 4; ct++) {
      short8 b = *(const short8*)(B2T + (size_t)(c0 + ct * 16 + l15) * K2 + q * 8 + ks * 32);
      acc2[ct] = __builtin_amdgcn_mfma_f32_16x16x32_bf16(a, b, acc2[ct], 0, 0, 0);
    }
  }

#pragma unroll
  for (int ct = 0; ct < 4; ct++) {
    int col = c0 + ct * 16 + l15;
#pragma unroll
    for (int r = 0; r < 4; r++) {
      float v = acc1[ct][r];
      v = v > 0.f ? v : __expf(v) - 1.f;         // elu on A1@B1
      v += acc2[ct][r];
      v = v > 0.f ? v : 0.f;                     // relu
      int row = row0 + q * 4 + r;
      if (F32OUT) ((float*)outv)[(size_t)row * NOUT + col] = v;
      else        ((bf16*)outv)[(size_t)row * NOUT + col] = __float2bfloat16(v);
    }
  }
}

// ---------------------------------------------------------------- launcher
extern "C" void kernel_launch(void* const* d_in, const int* in_sizes, int n_in,
                              void* d_out, int out_size, void* d_ws, size_t ws_size,
                              hipStream_t stream) {
  const float* x    = (const float*)d_in[0];
  const int*   adj  = (const int*)d_in[1];
  const float* W1   = (const float*)d_in[2];
  const float* a1s  = (const float*)d_in[3];
  const float* a1d  = (const float*)d_in[4];
  const float* lin1 = (const float*)d_in[5];
  const float* res1 = (const float*)d_in[6];
  const float* W2   = (const float*)d_in[7];
  const float* a2s  = (const float*)d_in[8];
  const float* a2d  = (const float*)d_in[9];
  const float* lin2 = (const float*)d_in[10];
  const float* res2 = (const float*)d_in[11];
  float* out = (float*)d_out;

  char* p = (char*)d_ws;
  auto alloc = [&](size_t bytes) { void* r = (void*)p; p += (bytes + 255) & ~(size_t)255; return r; };
  uint32_t* bits = (uint32_t*)alloc((size_t)N * NW * 4);
  bf16* xb    = (bf16*)alloc((size_t)N * D0 * 2);
  bf16* W1T   = (bf16*)alloc((size_t)HEADS * F1 * D0 * 2);
  bf16* lin1T = (bf16*)alloc((size_t)F1 * HEADS * F1 * 2);
  bf16* res1T = (bf16*)alloc((size_t)F1 * D0 * 2);
  bf16* W2T   = (bf16*)alloc((size_t)HEADS * F2 * F1 * 2);
  bf16* lin2T = (bf16*)alloc((size_t)F2 * HEADS * F2 * 2);
  bf16* res2T = (bf16*)alloc((size_t)F2 * F1 * 2);
  bf16* WhT1  = (bf16*)alloc((size_t)HEADS * F1 * N * 2);
  bf16* WhT2  = (bf16*)alloc((size_t)HEADS * F2 * N * 2);
  float* src1 = (float*)alloc((size_t)HEADS * N * 4);
  float* dst1 = (float*)alloc((size_t)HEADS * N * 4);
  float* src2 = (float*)alloc((size_t)HEADS * N * 4);
  float* dst2 = (float*)alloc((size_t)HEADS * N * 4);
  bf16* hp1   = (bf16*)alloc((size_t)N * HEADS * F1 * 2);
  bf16* hp2   = (bf16*)alloc((size_t)N * HEADS * F2 * 2);
  bf16* h1b   = (bf16*)alloc((size_t)N * F1 * 2);

  k_pack_adj<<<dim3(N * N / 256), dim3(256), 0, stream>>>(adj, bits);
  k_cvt<<<dim3(N * D0 / 256, 7), dim3(256), 0, stream>>>(x, W1, lin1, res1, W2, lin2, res2,
                                                         xb, W1T, lin1T, res1T, W2T, lin2T, res2T);

  // layer 1
  k_whead_mfma<D0, HEADS * F1><<<dim3(N / 64, HEADS * F1 / 64), dim3(256), 0, stream>>>(xb, W1T, WhT1);
  k_srcdst<F1><<<dim3(N / 256, HEADS), dim3(256), 0, stream>>>(WhT1, a1s, a1d, src1, dst1);
  k_attn_fused<F1><<<dim3(N / 16, HEADS), dim3(256), 0, stream>>>(WhT1, src1, dst1, bits, hp1);
  k_mix_mfma<HEADS * F1, D0, F1, false>
      <<<dim3(N / 64, F1 / 64), dim3(256), 0, stream>>>(hp1, lin1T, xb, res1T, h1b);

  // layer 2
  k_whead_mfma<F1, HEADS * F2><<<dim3(N / 64, HEADS * F2 / 64), dim3(256), 0, stream>>>(h1b, W2T, WhT2);
  k_srcdst<F2><<<dim3(N / 256, HEADS), dim3(256), 0, stream>>>(WhT2, a2s, a2d, src2, dst2);
  k_attn_fused<F2><<<dim3(N / 16, HEADS), dim3(256), 0, stream>>>(WhT2, src2, dst2, bits, hp2);
  k_mix_mfma<HEADS * F2, F1, F2, true>
      <<<dim3(N / 64, F2 / 64), dim3(256), 0, stream>>>(hp2, lin2T, h1b, res2T, out);
}